// Round 7
// baseline (227.101 us; speedup 1.0000x reference)
//
#include <hip/hip_runtime.h>
#include <math.h>

// Problem constants (match reference)
#define B_    8192
#define F_    64
#define V_    1000
#define E_    64
#define T_    2
#define NTOK_ 16
#define G_    4
#define D_    256
#define K_    128   // T*E
#define LN_EPS 1e-5f

#define RPB   2              // batch rows per block
#define TOK2  (NTOK_ * RPB)  // 32 tokens per block
#define XSP   136            // xs row stride in bf16 elements (128 + 8 pad)
#define HSP   260            // hs row stride in floats (256 + 4)

typedef __attribute__((ext_vector_type(8))) short  frag_ab;  // 8 bf16 = 4 VGPRs
typedef __attribute__((ext_vector_type(4))) float  frag_cd;  // 4 fp32 acc
typedef __attribute__((ext_vector_type(4))) float  f32x4;    // native vec4 (NT-store legal)

static __device__ __forceinline__ unsigned short f2bf(float f) {
    // round-to-nearest-even fp32 -> bf16 (values are finite here)
    unsigned int u = __float_as_uint(f);
    u += 0x7FFFu + ((u >> 16) & 1u);
    return (unsigned short)(u >> 16);
}

// ---- prologue: W fp32 (D,K) -> bf16 in workspace (row-major, same layout) ----
__global__ __launch_bounds__(256) void convert_w_kernel(const float* __restrict__ W,
                                                        unsigned int* __restrict__ Wb_packed) {
    const int i = blockIdx.x * 256 + threadIdx.x;   // one uint = 2 bf16
    if (i < (D_ * K_) / 2) {
        const float2 v = *(const float2*)(W + (size_t)i * 2);
        const unsigned int p = (unsigned int)f2bf(v.x) | ((unsigned int)f2bf(v.y) << 16);
        __builtin_nontemporal_store(p, Wb_packed + i);
    }
}

// One block per TWO batch rows (grid 4096). 256 threads = 4 waves.
// r6 proved ILP (2-row W reuse + explicit W double-buffer) is the MLP fix
// (113 -> 86.5 us at occupancy 40%). This version keeps that structure and
// restores occupancy by shrinking LDS 35.8KB -> ~19.7KB:
//  - two-pass epilogue: hs holds only 16 tokens (row0); row1's silu outputs
//    stay in 16 registers (statically indexed) and reuse hs after row0 is
//    stored. 33.3KB -> 16.6KB.
//  - gather address math replaced by a precomputed 256-entry byte-offset
//    table (1 entry/thread at setup): fewer VALU ops + fewer LDS reads in
//    the hot gather loop.
// Target: 7-8 blocks/CU (28-32 waves) with VGPR ~68 (launch_bounds cap 85).
__global__ __launch_bounds__(256, 6) void fused_tokenizer_kernel(
    const int*   __restrict__ int_feats,     // (B, F)
    const int*   __restrict__ missing_mask,  // (B, F)
    const int*   __restrict__ group_idx,     // (NTOK, G)
    const float* __restrict__ emb_tables,    // (T, F, V, E)
    const float* __restrict__ missing_emb,   // (T, F, E)
    const unsigned short* __restrict__ Wb,   // (D, K) bf16
    const float* __restrict__ bias,          // (D,)
    const float* __restrict__ gamma,         // (D,)
    const float* __restrict__ beta,          // (D,)
    float*       __restrict__ out)           // (B, NTOK, D)
{
    // hs[16][260] fp32 (16.6KB) aliases xs[32][136] bf16 (8.7KB): xs is dead
    // after the fragment loads; a barrier separates last xs read / first hs write.
    __shared__ __align__(16) char smem[NTOK_ * HSP * 4];
    unsigned short (*xs)[XSP] = (unsigned short (*)[XSP])smem;
    float          (*hs)[HSP] = (float (*)[HSP])smem;

    __shared__ unsigned int poff[RPB][T_][NTOK_][G_];  // emb_tables byte offsets (1KB)
    __shared__ unsigned int moff[T_][NTOK_][G_];       // missing_emb byte offsets (512B)
    __shared__ float        pmk [RPB][NTOK_][G_];      // missing mask as float   (512B)
    __shared__ float ps [TOK2][4];   // per-wave partial sum   (token, wave)
    __shared__ float pss[TOK2][4];   // per-wave partial sumsq

    const int tid  = threadIdx.x;
    const int b0   = blockIdx.x * RPB;
    const int lane = tid & 63;
    const int wave = tid >> 6;

    // ---- setup: one offset-table entry per thread ----
    {
        const int row = tid >> 7;          // 0..1
        const int t   = (tid >> 6) & 1;    // 0..1
        const int n   = (tid >> 2) & 15;   // token
        const int g   = tid & 3;           // slot in group
        const int f   = group_idx[n * G_ + g];
        const int id  = int_feats[(b0 + row) * F_ + f];
        poff[row][t][n][g] = (unsigned int)(((t * F_ + f) * V_ + id) * (E_ * 4));
        if (row == 0) moff[t][n][g] = (unsigned int)((t * F_ + f) * (E_ * 4));
        if (t == 0)   pmk[row][n][g] = (float)missing_mask[(b0 + row) * F_ + f];
    }
    __syncthreads();

    // ---- Phase 1: gather + mean-pool, 2 rows (1024 float4-chunks) ----
    // chunk c: row = c>>9, cc = c&511, n = cc>>5 (token), r4 = cc&31,
    // t = r4>>4, eb = (r4&15)*16 bytes. 16 consecutive lanes cover one 256B
    // embedding row -> coalesced dwordx4. Loads batched (branchless).
    const char* tbl = (const char*)emb_tables;
    const char* msb = (const char*)missing_emb;
#pragma unroll
    for (int i = 0; i < 4; ++i) {
        const int c   = i * 256 + tid;
        const int row = c >> 9;
        const int cc  = c & 511;
        const int n   = cc >> 5;
        const int r4  = cc & 31;
        const int t   = r4 >> 4;
        const int eb  = (r4 & 15) * 16;

        float4 ev[G_], mv[G_];
        float  mk[G_];
#pragma unroll
        for (int g = 0; g < G_; ++g) {
            ev[g] = *(const float4*)(tbl + poff[row][t][n][g] + eb);
            mv[g] = *(const float4*)(msb + moff[t][n][g] + eb);
            mk[g] = pmk[row][n][g];
        }
        float ax = 0.f, ay = 0.f, az = 0.f, aw = 0.f;
#pragma unroll
        for (int g = 0; g < G_; ++g) {
            ax += ev[g].x + mk[g] * mv[g].x;
            ay += ev[g].y + mk[g] * mv[g].y;
            az += ev[g].z + mk[g] * mv[g].z;
            aw += ev[g].w + mk[g] * mv[g].w;
        }
        union { unsigned int u[2]; } pk;
        pk.u[0] = (unsigned int)f2bf(0.25f * ax) | ((unsigned int)f2bf(0.25f * ay) << 16);
        pk.u[1] = (unsigned int)f2bf(0.25f * az) | ((unsigned int)f2bf(0.25f * aw) << 16);
        *(uint2*)(&xs[row * NTOK_ + n][r4 * 4]) = make_uint2(pk.u[0], pk.u[1]);
    }
    __syncthreads();

    // ---- Phase 2: swapped-operand MFMA, 2 rows sharing W fragments ----
    const int m = lane & 15;   // token index within a row (D col of MFMA result)
    const int q = lane >> 4;   // quadrant

    frag_ab a0[4], a1[4];
#pragma unroll
    for (int s = 0; s < 4; ++s) {
        a0[s] = *(const frag_ab*)(&xs[m][32 * s + 8 * q]);
        a1[s] = *(const frag_ab*)(&xs[NTOK_ + m][32 * s + 8 * q]);
    }
    __syncthreads();   // all waves' xs reads done before hs writes (aliased)

    float s0 = 0.f, ss0 = 0.f, s1 = 0.f, ss1 = 0.f;
    float4 h1r[4];     // row1 silu outputs, kept in registers (static indexing)

    frag_ab wb_[2][4];
    {
        const unsigned short* wp = Wb + (size_t)((wave * 4 + 0) * 16 + m) * K_ + 8 * q;
#pragma unroll
        for (int s = 0; s < 4; ++s) wb_[0][s] = *(const frag_ab*)(wp + 32 * s);
    }

#pragma unroll
    for (int tt = 0; tt < 4; ++tt) {
        const int cur = tt & 1;           // compile-time after unroll
        if (tt < 3) {
            const unsigned short* wp = Wb + (size_t)((wave * 4 + tt + 1) * 16 + m) * K_ + 8 * q;
#pragma unroll
            for (int s = 0; s < 4; ++s) wb_[cur ^ 1][s] = *(const frag_ab*)(wp + 32 * s);
        }
        frag_cd acc0 = {0.f, 0.f, 0.f, 0.f};
        frag_cd acc1 = {0.f, 0.f, 0.f, 0.f};
#pragma unroll
        for (int s = 0; s < 4; ++s) {
            acc0 = __builtin_amdgcn_mfma_f32_16x16x32_bf16(wb_[cur][s], a0[s], acc0, 0, 0, 0);
            acc1 = __builtin_amdgcn_mfma_f32_16x16x32_bf16(wb_[cur][s], a1[s], acc1, 0, 0, 0);
        }
        const int col = (wave * 4 + tt) * 16 + q * 4;
        const float4 bn = *(const float4*)(bias + col);
        const float bnv[4] = {bn.x, bn.y, bn.z, bn.w};
        float4 h0;
#pragma unroll
        for (int reg = 0; reg < 4; ++reg) {
            const float z0 = acc0[reg] + bnv[reg];
            const float z1 = acc1[reg] + bnv[reg];
            const float v0 = z0 / (1.f + __expf(-z0));   // silu
            const float v1 = z1 / (1.f + __expf(-z1));
            s0 += v0; ss0 += v0 * v0;
            s1 += v1; ss1 += v1 * v1;
            ((float*)&h0)[reg]      = v0;
            ((float*)&h1r[tt])[reg] = v1;
        }
        *(float4*)(&hs[m][col]) = h0;   // row0 raw silu; LN applied at readout
    }

    // reduce across the 4 lanes holding token m (lanes m, m+16, m+32, m+48)
    s0  += __shfl_xor(s0,  16, 64);  ss0 += __shfl_xor(ss0, 16, 64);
    s0  += __shfl_xor(s0,  32, 64);  ss0 += __shfl_xor(ss0, 32, 64);
    s1  += __shfl_xor(s1,  16, 64);  ss1 += __shfl_xor(ss1, 16, 64);
    s1  += __shfl_xor(s1,  32, 64);  ss1 += __shfl_xor(ss1, 32, 64);
    if (q == 0) {
        ps [m][wave]         = s0;  pss[m][wave]         = ss0;
        ps [NTOK_ + m][wave] = s1;  pss[NTOK_ + m][wave] = ss1;
    }
    __syncthreads();

    // ---- Phase 3a: LN + NT store, row0; wave w handles tokens 4w..4w+3 ----
    const float4 gm = *(const float4*)(gamma + lane * 4);
    const float4 bt = *(const float4*)(beta  + lane * 4);
#pragma unroll
    for (int qq = 0; qq < 4; ++qq) {
        const int n = wave * 4 + qq;            // 0..15
        const float4 p4  = *(const float4*)(&ps[n][0]);
        const float4 pq4 = *(const float4*)(&pss[n][0]);
        const float s_tot  = (p4.x  + p4.y)  + (p4.z  + p4.w);
        const float ss_tot = (pq4.x + pq4.y) + (pq4.z + pq4.w);
        const float mu   = s_tot * (1.f / D_);
        const float var  = ss_tot * (1.f / D_) - mu * mu;
        const float rsig = rsqrtf(var + LN_EPS);

        const float4 v = *(const float4*)(&hs[n][lane * 4]);
        f32x4 o;
        o.x = (v.x - mu) * rsig * gm.x + bt.x;
        o.y = (v.y - mu) * rsig * gm.y + bt.y;
        o.z = (v.z - mu) * rsig * gm.z + bt.z;
        o.w = (v.w - mu) * rsig * gm.w + bt.w;
        __builtin_nontemporal_store(o, (f32x4*)(out + ((size_t)b0 * NTOK_ + n) * D_ + lane * 4));
    }
    __syncthreads();   // row0 fully read from hs

    // ---- dump row1 registers into hs (same layout) ----
#pragma unroll
    for (int tt = 0; tt < 4; ++tt) {
        const int col = (wave * 4 + tt) * 16 + q * 4;
        *(float4*)(&hs[m][col]) = h1r[tt];
    }
    __syncthreads();

    // ---- Phase 3b: LN + NT store, row1 ----
#pragma unroll
    for (int qq = 0; qq < 4; ++qq) {
        const int n = wave * 4 + qq;            // 0..15
        const float4 p4  = *(const float4*)(&ps[NTOK_ + n][0]);
        const float4 pq4 = *(const float4*)(&pss[NTOK_ + n][0]);
        const float s_tot  = (p4.x  + p4.y)  + (p4.z  + p4.w);
        const float ss_tot = (pq4.x + pq4.y) + (pq4.z + pq4.w);
        const float mu   = s_tot * (1.f / D_);
        const float var  = ss_tot * (1.f / D_) - mu * mu;
        const float rsig = rsqrtf(var + LN_EPS);

        const float4 v = *(const float4*)(&hs[n][lane * 4]);
        f32x4 o;
        o.x = (v.x - mu) * rsig * gm.x + bt.x;
        o.y = (v.y - mu) * rsig * gm.y + bt.y;
        o.z = (v.z - mu) * rsig * gm.z + bt.z;
        o.w = (v.w - mu) * rsig * gm.w + bt.w;
        __builtin_nontemporal_store(o, (f32x4*)(out + ((size_t)(b0 + 1) * NTOK_ + n) * D_ + lane * 4));
    }
}

extern "C" void kernel_launch(void* const* d_in, const int* in_sizes, int n_in,
                              void* d_out, int out_size, void* d_ws, size_t ws_size,
                              hipStream_t stream) {
    const int*   int_feats    = (const int*)  d_in[0];
    const int*   missing_mask = (const int*)  d_in[1];
    const int*   group_idx    = (const int*)  d_in[2];
    const float* emb_tables   = (const float*)d_in[3];
    const float* missing_emb  = (const float*)d_in[4];
    const float* W            = (const float*)d_in[5];
    const float* bias         = (const float*)d_in[6];
    const float* gamma        = (const float*)d_in[7];
    const float* beta         = (const float*)d_in[8];
    float* out = (float*)d_out;

    unsigned short* Wb = (unsigned short*)d_ws;   // 64 KB bf16 copy of W

    convert_w_kernel<<<(D_ * K_ / 2 + 255) / 256, 256, 0, stream>>>(W, (unsigned int*)Wb);
    fused_tokenizer_kernel<<<B_ / RPB, 256, 0, stream>>>(
        int_feats, missing_mask, group_idx, emb_tables, missing_emb,
        Wb, bias, gamma, beta, out);
}

// Round 8
// 224.895 us; speedup vs baseline: 1.0098x; 1.0098x over previous
//
#include <hip/hip_runtime.h>
#include <math.h>

// Problem constants (match reference)
#define B_    8192
#define F_    64
#define V_    1000
#define E_    64
#define T_    2
#define NTOK_ 16
#define G_    4
#define D_    256
#define K_    128   // T*E
#define LN_EPS 1e-5f

#define RPB   2              // batch rows per block
#define TOK2  (NTOK_ * RPB)  // 32 tokens per block
#define XSP   136            // xs row stride in bf16 elements (128 + 8 pad)
#define HSP   260            // hs row stride in floats (256 + 4)

typedef __attribute__((ext_vector_type(8))) short  frag_ab;  // 8 bf16 = 4 VGPRs
typedef __attribute__((ext_vector_type(4))) float  frag_cd;  // 4 fp32 acc
typedef __attribute__((ext_vector_type(4))) float  f32x4;    // native vec4 (NT-store legal)

static __device__ __forceinline__ unsigned short f2bf(float f) {
    // round-to-nearest-even fp32 -> bf16 (values are finite here)
    unsigned int u = __float_as_uint(f);
    u += 0x7FFFu + ((u >> 16) & 1u);
    return (unsigned short)(u >> 16);
}

// ---- prologue: W fp32 (D,K) -> bf16 in workspace (row-major, same layout) ----
__global__ __launch_bounds__(256) void convert_w_kernel(const float* __restrict__ W,
                                                        unsigned int* __restrict__ Wb_packed) {
    const int i = blockIdx.x * 256 + threadIdx.x;   // one uint = 2 bf16
    if (i < (D_ * K_) / 2) {
        const float2 v = *(const float2*)(W + (size_t)i * 2);
        const unsigned int p = (unsigned int)f2bf(v.x) | ((unsigned int)f2bf(v.y) << 16);
        __builtin_nontemporal_store(p, Wb_packed + i);
    }
}

// Gather pipeline stage: 8 loads + metadata, fully register-resident
// (statically indexed everywhere after inlining).
struct GStage {
    float4 ev[G_], mv[G_];
    float  mk[G_];
    int    row, n, r4;
};

static __device__ __forceinline__ void g_issue(
    int c, GStage& st, const int* sg, const int (*sid)[F_], const int (*smask)[F_],
    const float* __restrict__ emb_tables, const float* __restrict__ missing_emb)
{
    st.row = c >> 9;
    const int cc = c & 511;
    st.n  = cc >> 5;
    st.r4 = cc & 31;
    const int t = st.r4 >> 4;
    const int e = (st.r4 & 15) * 4;
#pragma unroll
    for (int g = 0; g < G_; ++g) {
        const int f  = sg[st.n * G_ + g];
        const int id = sid[st.row][f];
        st.ev[g] = *(const float4*)(emb_tables + (((size_t)(t * F_ + f) * V_) + id) * E_ + e);
        st.mv[g] = *(const float4*)(missing_emb + (size_t)(t * F_ + f) * E_ + e);
        st.mk[g] = (float)smask[st.row][f];
    }
}

static __device__ __forceinline__ void g_pool_store(const GStage& st, unsigned short (*xs)[XSP]) {
    float ax = 0.f, ay = 0.f, az = 0.f, aw = 0.f;
#pragma unroll
    for (int g = 0; g < G_; ++g) {
        ax += st.ev[g].x + st.mk[g] * st.mv[g].x;
        ay += st.ev[g].y + st.mk[g] * st.mv[g].y;
        az += st.ev[g].z + st.mk[g] * st.mv[g].z;
        aw += st.ev[g].w + st.mk[g] * st.mv[g].w;
    }
    union { unsigned int u[2]; } pk;
    pk.u[0] = (unsigned int)f2bf(0.25f * ax) | ((unsigned int)f2bf(0.25f * ay) << 16);
    pk.u[1] = (unsigned int)f2bf(0.25f * az) | ((unsigned int)f2bf(0.25f * aw) << 16);
    *(uint2*)(&xs[st.row * NTOK_ + st.n][st.r4 * 4]) = make_uint2(pk.u[0], pk.u[1]);
}

// One block per TWO batch rows (grid 4096). 256 threads = 4 waves.
// r6 structure (proven 86.5us): 2-row W reuse + explicit W double-buffer,
// deferred LN, single-pass epilogue, launch_bounds(256,4), LDS 35.8KB.
// r8 change: the gather is software-pipelined at depth 2 (two register
// stages; stage B's 8 loads issue before stage A is pooled) — same ILP
// lever that fixed the MLP, applied to phase 1. Exposed gather latency
// per thread ~halves; VGPR grows ~50 (under the 128 cap).
__global__ __launch_bounds__(256, 4) void fused_tokenizer_kernel(
    const int*   __restrict__ int_feats,     // (B, F)
    const int*   __restrict__ missing_mask,  // (B, F)
    const int*   __restrict__ group_idx,     // (NTOK, G)
    const float* __restrict__ emb_tables,    // (T, F, V, E)
    const float* __restrict__ missing_emb,   // (T, F, E)
    const unsigned short* __restrict__ Wb,   // (D, K) bf16
    const float* __restrict__ bias,          // (D,)
    const float* __restrict__ gamma,         // (D,)
    const float* __restrict__ beta,          // (D,)
    float*       __restrict__ out)           // (B, NTOK, D)
{
    // hs (32x260 fp32 = 33.3 KB) aliases xs (32x136 bf16 = 8.7 KB).
    __shared__ __align__(16) char smem[TOK2 * HSP * 4];
    unsigned short (*xs)[XSP] = (unsigned short (*)[XSP])smem;
    float          (*hs)[HSP] = (float (*)[HSP])smem;

    __shared__ int   sid[RPB][F_];
    __shared__ int   smask[RPB][F_];
    __shared__ int   sg[NTOK_ * G_];
    __shared__ float ps [TOK2][4];   // per-wave partial sum   (token, wave)
    __shared__ float pss[TOK2][4];   // per-wave partial sumsq

    const int tid  = threadIdx.x;
    const int b0   = blockIdx.x * RPB;
    const int lane = tid & 63;
    const int wave = tid >> 6;

    if (tid < RPB * F_) {
        const int r = tid >> 6, f = tid & 63;
        sid[r][f]   = int_feats[(b0 + r) * F_ + f];
        smask[r][f] = missing_mask[(b0 + r) * F_ + f];
    }
    if (tid < F_) sg[tid] = group_idx[tid];   // NTOK*G == F == 64
    __syncthreads();

    // ---- Phase 1: gather + mean-pool, depth-2 software pipeline ----
    // chunk c: row = c>>9, cc = c&511, n = cc>>5 (token), r4 = cc&31.
    // 16 consecutive lanes cover one 256B embedding row -> coalesced dwordx4.
    {
        GStage sA, sB;
        g_issue(tid,       sA, sg, sid, smask, emb_tables, missing_emb);
        g_issue(256 + tid, sB, sg, sid, smask, emb_tables, missing_emb);
        g_pool_store(sA, xs);
        g_issue(512 + tid, sA, sg, sid, smask, emb_tables, missing_emb);
        g_pool_store(sB, xs);
        g_issue(768 + tid, sB, sg, sid, smask, emb_tables, missing_emb);
        g_pool_store(sA, xs);
        g_pool_store(sB, xs);
    }
    __syncthreads();

    // ---- Phase 2: swapped-operand MFMA, 2 rows sharing W fragments ----
    const int m = lane & 15;   // token index within a row (D col of MFMA result)
    const int q = lane >> 4;   // quadrant

    frag_ab a0[4], a1[4];
#pragma unroll
    for (int s = 0; s < 4; ++s) {
        a0[s] = *(const frag_ab*)(&xs[m][32 * s + 8 * q]);
        a1[s] = *(const frag_ab*)(&xs[NTOK_ + m][32 * s + 8 * q]);
    }
    __syncthreads();   // all waves' xs reads done before hs writes (aliased)

    float s0 = 0.f, ss0 = 0.f, s1 = 0.f, ss1 = 0.f;

    frag_ab wb_[2][4];
    {
        const unsigned short* wp = Wb + (size_t)((wave * 4 + 0) * 16 + m) * K_ + 8 * q;
#pragma unroll
        for (int s = 0; s < 4; ++s) wb_[0][s] = *(const frag_ab*)(wp + 32 * s);
    }

#pragma unroll
    for (int tt = 0; tt < 4; ++tt) {
        const int cur = tt & 1;           // compile-time after unroll
        if (tt < 3) {
            const unsigned short* wp = Wb + (size_t)((wave * 4 + tt + 1) * 16 + m) * K_ + 8 * q;
#pragma unroll
            for (int s = 0; s < 4; ++s) wb_[cur ^ 1][s] = *(const frag_ab*)(wp + 32 * s);
        }
        frag_cd acc0 = {0.f, 0.f, 0.f, 0.f};
        frag_cd acc1 = {0.f, 0.f, 0.f, 0.f};
#pragma unroll
        for (int s = 0; s < 4; ++s) {
            acc0 = __builtin_amdgcn_mfma_f32_16x16x32_bf16(wb_[cur][s], a0[s], acc0, 0, 0, 0);
            acc1 = __builtin_amdgcn_mfma_f32_16x16x32_bf16(wb_[cur][s], a1[s], acc1, 0, 0, 0);
        }
        const int nt  = wave * 4 + tt;
        const int col = nt * 16 + q * 4;
        const float4 bn = *(const float4*)(bias + col);
        const float bnv[4] = {bn.x, bn.y, bn.z, bn.w};
        float4 h0, h1;
#pragma unroll
        for (int reg = 0; reg < 4; ++reg) {
            const float z0 = acc0[reg] + bnv[reg];
            const float z1 = acc1[reg] + bnv[reg];
            const float v0 = z0 / (1.f + __expf(-z0));   // silu
            const float v1 = z1 / (1.f + __expf(-z1));
            s0 += v0; ss0 += v0 * v0;
            s1 += v1; ss1 += v1 * v1;
            ((float*)&h0)[reg] = v0;
            ((float*)&h1)[reg] = v1;
        }
        *(float4*)(&hs[m][col])         = h0;   // raw silu; LN applied at readout
        *(float4*)(&hs[NTOK_ + m][col]) = h1;
    }

    // reduce across the 4 lanes holding token m (lanes m, m+16, m+32, m+48)
    s0  += __shfl_xor(s0,  16, 64);  ss0 += __shfl_xor(ss0, 16, 64);
    s0  += __shfl_xor(s0,  32, 64);  ss0 += __shfl_xor(ss0, 32, 64);
    s1  += __shfl_xor(s1,  16, 64);  ss1 += __shfl_xor(ss1, 16, 64);
    s1  += __shfl_xor(s1,  32, 64);  ss1 += __shfl_xor(ss1, 32, 64);
    if (q == 0) {
        ps [m][wave]         = s0;  pss[m][wave]         = ss0;
        ps [NTOK_ + m][wave] = s1;  pss[NTOK_ + m][wave] = ss1;
    }
    __syncthreads();

    // ---- Phase 3: LN at readout + coalesced NT stores; wave w: tokens 8w..8w+7 ----
    const float4 gm = *(const float4*)(gamma + lane * 4);
    const float4 bt = *(const float4*)(beta  + lane * 4);
#pragma unroll
    for (int qq = 0; qq < 8; ++qq) {
        const int n = wave * 8 + qq;            // 0..31
        const float4 p4  = *(const float4*)(&ps[n][0]);
        const float4 pq4 = *(const float4*)(&pss[n][0]);
        const float s_tot  = (p4.x  + p4.y)  + (p4.z  + p4.w);
        const float ss_tot = (pq4.x + pq4.y) + (pq4.z + pq4.w);
        const float mu   = s_tot * (1.f / D_);
        const float var  = ss_tot * (1.f / D_) - mu * mu;
        const float rsig = rsqrtf(var + LN_EPS);

        const float4 v = *(const float4*)(&hs[n][lane * 4]);
        f32x4 o;
        o.x = (v.x - mu) * rsig * gm.x + bt.x;
        o.y = (v.y - mu) * rsig * gm.y + bt.y;
        o.z = (v.z - mu) * rsig * gm.z + bt.z;
        o.w = (v.w - mu) * rsig * gm.w + bt.w;
        const size_t orow = ((size_t)(b0 + (n >> 4)) * NTOK_ + (n & 15)) * D_;
        __builtin_nontemporal_store(o, (f32x4*)(out + orow + lane * 4));
    }
}

extern "C" void kernel_launch(void* const* d_in, const int* in_sizes, int n_in,
                              void* d_out, int out_size, void* d_ws, size_t ws_size,
                              hipStream_t stream) {
    const int*   int_feats    = (const int*)  d_in[0];
    const int*   missing_mask = (const int*)  d_in[1];
    const int*   group_idx    = (const int*)  d_in[2];
    const float* emb_tables   = (const float*)d_in[3];
    const float* missing_emb  = (const float*)d_in[4];
    const float* W            = (const float*)d_in[5];
    const float* bias         = (const float*)d_in[6];
    const float* gamma        = (const float*)d_in[7];
    const float* beta         = (const float*)d_in[8];
    float* out = (float*)d_out;

    unsigned short* Wb = (unsigned short*)d_ws;   // 64 KB bf16 copy of W

    convert_w_kernel<<<(D_ * K_ / 2 + 255) / 256, 256, 0, stream>>>(W, (unsigned int*)Wb);
    fused_tokenizer_kernel<<<B_ / RPB, 256, 0, stream>>>(
        int_feats, missing_mask, group_idx, emb_tables, missing_emb,
        Wb, bias, gamma, beta, out);
}

// Round 9
// 221.633 us; speedup vs baseline: 1.0247x; 1.0147x over previous
//
#include <hip/hip_runtime.h>
#include <math.h>

// Problem constants (match reference)
#define B_    8192
#define F_    64
#define V_    1000
#define E_    64
#define T_    2
#define NTOK_ 16
#define G_    4
#define D_    256
#define K_    128   // T*E
#define LN_EPS 1e-5f

#define RPB   2              // batch rows per block
#define TOK2  (NTOK_ * RPB)  // 32 tokens per block
#define XSP   136            // xs row stride in bf16 elements (128 + 8 pad)
#define HSP   260            // hs row stride in floats (256 + 4)

typedef __attribute__((ext_vector_type(8))) short    frag_ab;  // 8 bf16 = 4 VGPRs
typedef __attribute__((ext_vector_type(4))) float    frag_cd;  // 4 fp32 acc
typedef __attribute__((ext_vector_type(4))) float    f32x4;    // native vec4 (NT-store legal)
typedef __attribute__((ext_vector_type(8))) _Float16 h8;       // 8 fp16 = 16B

static __device__ __forceinline__ unsigned short f2bf(float f) {
    // round-to-nearest-even fp32 -> bf16 (values are finite here)
    unsigned int u = __float_as_uint(f);
    u += 0x7FFFu + ((u >> 16) & 1u);
    return (unsigned short)(u >> 16);
}

// ---- prologue: W fp32 (D,K) -> bf16 in workspace (row-major, same layout) ----
__global__ __launch_bounds__(256) void convert_w_kernel(const float* __restrict__ W,
                                                        unsigned int* __restrict__ Wb_packed) {
    const int i = blockIdx.x * 256 + threadIdx.x;   // one uint = 2 bf16
    if (i < (D_ * K_) / 2) {
        const float2 v = *(const float2*)(W + (size_t)i * 2);
        const unsigned int p = (unsigned int)f2bf(v.x) | ((unsigned int)f2bf(v.y) << 16);
        __builtin_nontemporal_store(p, Wb_packed + i);
    }
}

// ---- prologue: generic fp32 -> fp16 (RNE), 8 elems/thread ----
__global__ __launch_bounds__(256) void convert_f16_kernel(const float* __restrict__ src,
                                                          _Float16* __restrict__ dst, int n8) {
    const int i = blockIdx.x * 256 + threadIdx.x;
    if (i < n8) {
        const float4 a = *(const float4*)(src + (size_t)i * 8);
        const float4 b = *(const float4*)(src + (size_t)i * 8 + 4);
        h8 o;
        o[0] = (_Float16)a.x; o[1] = (_Float16)a.y; o[2] = (_Float16)a.z; o[3] = (_Float16)a.w;
        o[4] = (_Float16)b.x; o[5] = (_Float16)b.y; o[6] = (_Float16)b.z; o[7] = (_Float16)b.w;
        *(h8*)(dst + (size_t)i * 8) = o;
    }
}

// One block per TWO batch rows (grid 4096). 256 threads = 4 waves.
// r6 structure (proven 86.5us dispatch): 2-row W reuse + explicit W double-
// buffer, deferred LN, launch_bounds(256,4), LDS 35.8KB, NT out stores.
// r9 change: gather reads a FP16 copy of emb_tables/missing_emb (prologue-
// converted). Halves gather bytes AND load count (h8 = 8 elems/16B vs
// float4 = 4 elems/16B); 16.8MB table now L3-resident under the output
// stream (r6 FETCH was 119MB vs 38MB compulsory = table thrash).
__global__ __launch_bounds__(256, 4) void fused_tokenizer_kernel(
    const int*   __restrict__ int_feats,     // (B, F)
    const int*   __restrict__ missing_mask,  // (B, F)
    const int*   __restrict__ group_idx,     // (NTOK, G)
    const _Float16* __restrict__ tblh,       // (T, F, V, E) fp16
    const _Float16* __restrict__ mish,       // (T, F, E)    fp16
    const unsigned short* __restrict__ Wb,   // (D, K) bf16
    const float* __restrict__ bias,          // (D,)
    const float* __restrict__ gamma,         // (D,)
    const float* __restrict__ beta,          // (D,)
    float*       __restrict__ out)           // (B, NTOK, D)
{
    // hs (32x260 fp32 = 33.3 KB) aliases xs (32x136 bf16 = 8.7 KB).
    __shared__ __align__(16) char smem[TOK2 * HSP * 4];
    unsigned short (*xs)[XSP] = (unsigned short (*)[XSP])smem;
    float          (*hs)[HSP] = (float (*)[HSP])smem;

    __shared__ int   sid[RPB][F_];
    __shared__ int   smask[RPB][F_];
    __shared__ int   sg[NTOK_ * G_];
    __shared__ float ps [TOK2][4];   // per-wave partial sum   (token, wave)
    __shared__ float pss[TOK2][4];   // per-wave partial sumsq

    const int tid  = threadIdx.x;
    const int b0   = blockIdx.x * RPB;
    const int lane = tid & 63;
    const int wave = tid >> 6;

    if (tid < RPB * F_) {
        const int r = tid >> 6, f = tid & 63;
        sid[r][f]   = int_feats[(b0 + r) * F_ + f];
        smask[r][f] = missing_mask[(b0 + r) * F_ + f];
    }
    if (tid < F_) sg[tid] = group_idx[tid];   // NTOK*G == F == 64
    __syncthreads();

    // ---- Phase 1: fp16 gather + mean-pool, 2 rows (512 h8-chunks) ----
    // chunk c: row = c>>8, n = (c>>4)&15, t = (c>>3)&1, e8 = c&7.
    // 8 consecutive lanes cover one 128B fp16 embedding row -> coalesced dwordx4.
#pragma unroll
    for (int i = 0; i < 2; ++i) {
        const int c   = i * 256 + tid;
        const int row = c >> 8;
        const int n   = (c >> 4) & 15;
        const int t   = (c >> 3) & 1;
        const int e8  = c & 7;

        h8    ev[G_], mv[G_];
        float mk[G_];
#pragma unroll
        for (int g = 0; g < G_; ++g) {
            const int f  = sg[n * G_ + g];
            const int id = sid[row][f];
            ev[g] = *(const h8*)(tblh + ((size_t)((t * F_ + f) * V_) + id) * E_ + e8 * 8);
            mv[g] = *(const h8*)(mish + (size_t)(t * F_ + f) * E_ + e8 * 8);
            mk[g] = (float)smask[row][f];
        }
        float acc[8] = {0.f, 0.f, 0.f, 0.f, 0.f, 0.f, 0.f, 0.f};
#pragma unroll
        for (int g = 0; g < G_; ++g)
#pragma unroll
            for (int j = 0; j < 8; ++j)
                acc[j] += (float)ev[g][j] + mk[g] * (float)mv[g][j];
        unsigned int pk[4];
#pragma unroll
        for (int jj = 0; jj < 4; ++jj)
            pk[jj] = (unsigned int)f2bf(0.25f * acc[2 * jj])
                   | ((unsigned int)f2bf(0.25f * acc[2 * jj + 1]) << 16);
        *(uint4*)(&xs[row * NTOK_ + n][(t * 8 + e8) * 8]) = make_uint4(pk[0], pk[1], pk[2], pk[3]);
    }
    __syncthreads();

    // ---- Phase 2: swapped-operand MFMA, 2 rows sharing W fragments ----
    const int m = lane & 15;   // token index within a row (D col of MFMA result)
    const int q = lane >> 4;   // quadrant

    frag_ab a0[4], a1[4];
#pragma unroll
    for (int s = 0; s < 4; ++s) {
        a0[s] = *(const frag_ab*)(&xs[m][32 * s + 8 * q]);
        a1[s] = *(const frag_ab*)(&xs[NTOK_ + m][32 * s + 8 * q]);
    }
    __syncthreads();   // all waves' xs reads done before hs writes (aliased)

    float s0 = 0.f, ss0 = 0.f, s1 = 0.f, ss1 = 0.f;

    frag_ab wb_[2][4];
    {
        const unsigned short* wp = Wb + (size_t)((wave * 4 + 0) * 16 + m) * K_ + 8 * q;
#pragma unroll
        for (int s = 0; s < 4; ++s) wb_[0][s] = *(const frag_ab*)(wp + 32 * s);
    }

#pragma unroll
    for (int tt = 0; tt < 4; ++tt) {
        const int cur = tt & 1;           // compile-time after unroll
        if (tt < 3) {
            const unsigned short* wp = Wb + (size_t)((wave * 4 + tt + 1) * 16 + m) * K_ + 8 * q;
#pragma unroll
            for (int s = 0; s < 4; ++s) wb_[cur ^ 1][s] = *(const frag_ab*)(wp + 32 * s);
        }
        frag_cd acc0 = {0.f, 0.f, 0.f, 0.f};
        frag_cd acc1 = {0.f, 0.f, 0.f, 0.f};
#pragma unroll
        for (int s = 0; s < 4; ++s) {
            acc0 = __builtin_amdgcn_mfma_f32_16x16x32_bf16(wb_[cur][s], a0[s], acc0, 0, 0, 0);
            acc1 = __builtin_amdgcn_mfma_f32_16x16x32_bf16(wb_[cur][s], a1[s], acc1, 0, 0, 0);
        }
        const int nt  = wave * 4 + tt;
        const int col = nt * 16 + q * 4;
        const float4 bn = *(const float4*)(bias + col);
        const float bnv[4] = {bn.x, bn.y, bn.z, bn.w};
        float4 h0, h1;
#pragma unroll
        for (int reg = 0; reg < 4; ++reg) {
            const float z0 = acc0[reg] + bnv[reg];
            const float z1 = acc1[reg] + bnv[reg];
            const float v0 = z0 / (1.f + __expf(-z0));   // silu
            const float v1 = z1 / (1.f + __expf(-z1));
            s0 += v0; ss0 += v0 * v0;
            s1 += v1; ss1 += v1 * v1;
            ((float*)&h0)[reg] = v0;
            ((float*)&h1)[reg] = v1;
        }
        *(float4*)(&hs[m][col])         = h0;   // raw silu; LN applied at readout
        *(float4*)(&hs[NTOK_ + m][col]) = h1;
    }

    // reduce across the 4 lanes holding token m (lanes m, m+16, m+32, m+48)
    s0  += __shfl_xor(s0,  16, 64);  ss0 += __shfl_xor(ss0, 16, 64);
    s0  += __shfl_xor(s0,  32, 64);  ss0 += __shfl_xor(ss0, 32, 64);
    s1  += __shfl_xor(s1,  16, 64);  ss1 += __shfl_xor(ss1, 16, 64);
    s1  += __shfl_xor(s1,  32, 64);  ss1 += __shfl_xor(ss1, 32, 64);
    if (q == 0) {
        ps [m][wave]         = s0;  pss[m][wave]         = ss0;
        ps [NTOK_ + m][wave] = s1;  pss[NTOK_ + m][wave] = ss1;
    }
    __syncthreads();

    // ---- Phase 3: LN at readout + coalesced NT stores; wave w: tokens 8w..8w+7 ----
    const float4 gm = *(const float4*)(gamma + lane * 4);
    const float4 bt = *(const float4*)(beta  + lane * 4);
#pragma unroll
    for (int qq = 0; qq < 8; ++qq) {
        const int n = wave * 8 + qq;            // 0..31
        const float4 p4  = *(const float4*)(&ps[n][0]);
        const float4 pq4 = *(const float4*)(&pss[n][0]);
        const float s_tot  = (p4.x  + p4.y)  + (p4.z  + p4.w);
        const float ss_tot = (pq4.x + pq4.y) + (pq4.z + pq4.w);
        const float mu   = s_tot * (1.f / D_);
        const float var  = ss_tot * (1.f / D_) - mu * mu;
        const float rsig = rsqrtf(var + LN_EPS);

        const float4 v = *(const float4*)(&hs[n][lane * 4]);
        f32x4 o;
        o.x = (v.x - mu) * rsig * gm.x + bt.x;
        o.y = (v.y - mu) * rsig * gm.y + bt.y;
        o.z = (v.z - mu) * rsig * gm.z + bt.z;
        o.w = (v.w - mu) * rsig * gm.w + bt.w;
        const size_t orow = ((size_t)(b0 + (n >> 4)) * NTOK_ + (n & 15)) * D_;
        __builtin_nontemporal_store(o, (f32x4*)(out + orow + lane * 4));
    }
}

// ================= Fallback (fp32 gather, r6-proven) — used only if ws too small
__global__ __launch_bounds__(256, 4) void fused_tokenizer_fp32_kernel(
    const int*   __restrict__ int_feats,
    const int*   __restrict__ missing_mask,
    const int*   __restrict__ group_idx,
    const float* __restrict__ emb_tables,
    const float* __restrict__ missing_emb,
    const unsigned short* __restrict__ Wb,
    const float* __restrict__ bias,
    const float* __restrict__ gamma,
    const float* __restrict__ beta,
    float*       __restrict__ out)
{
    __shared__ __align__(16) char smem[TOK2 * HSP * 4];
    unsigned short (*xs)[XSP] = (unsigned short (*)[XSP])smem;
    float          (*hs)[HSP] = (float (*)[HSP])smem;

    __shared__ int   sid[RPB][F_];
    __shared__ int   smask[RPB][F_];
    __shared__ int   sg[NTOK_ * G_];
    __shared__ float ps [TOK2][4];
    __shared__ float pss[TOK2][4];

    const int tid  = threadIdx.x;
    const int b0   = blockIdx.x * RPB;
    const int lane = tid & 63;
    const int wave = tid >> 6;

    if (tid < RPB * F_) {
        const int r = tid >> 6, f = tid & 63;
        sid[r][f]   = int_feats[(b0 + r) * F_ + f];
        smask[r][f] = missing_mask[(b0 + r) * F_ + f];
    }
    if (tid < F_) sg[tid] = group_idx[tid];
    __syncthreads();

#pragma unroll
    for (int i = 0; i < 4; ++i) {
        const int c   = i * 256 + tid;
        const int row = c >> 9;
        const int cc  = c & 511;
        const int n   = cc >> 5;
        const int r4  = cc & 31;
        const int t   = r4 >> 4;
        const int e   = (r4 & 15) * 4;

        float4 ev[G_], mv[G_];
        float  mk[G_];
#pragma unroll
        for (int g = 0; g < G_; ++g) {
            const int f  = sg[n * G_ + g];
            const int id = sid[row][f];
            ev[g] = *(const float4*)(emb_tables + (((size_t)(t * F_ + f) * V_) + id) * E_ + e);
            mv[g] = *(const float4*)(missing_emb + (size_t)(t * F_ + f) * E_ + e);
            mk[g] = (float)smask[row][f];
        }
        float ax = 0.f, ay = 0.f, az = 0.f, aw = 0.f;
#pragma unroll
        for (int g = 0; g < G_; ++g) {
            ax += ev[g].x + mk[g] * mv[g].x;
            ay += ev[g].y + mk[g] * mv[g].y;
            az += ev[g].z + mk[g] * mv[g].z;
            aw += ev[g].w + mk[g] * mv[g].w;
        }
        union { unsigned int u[2]; } pk;
        pk.u[0] = (unsigned int)f2bf(0.25f * ax) | ((unsigned int)f2bf(0.25f * ay) << 16);
        pk.u[1] = (unsigned int)f2bf(0.25f * az) | ((unsigned int)f2bf(0.25f * aw) << 16);
        *(uint2*)(&xs[row * NTOK_ + n][r4 * 4]) = make_uint2(pk.u[0], pk.u[1]);
    }
    __syncthreads();

    const int m = lane & 15;
    const int q = lane >> 4;

    frag_ab a0[4], a1[4];
#pragma unroll
    for (int s = 0; s < 4; ++s) {
        a0[s] = *(const frag_ab*)(&xs[m][32 * s + 8 * q]);
        a1[s] = *(const frag_ab*)(&xs[NTOK_ + m][32 * s + 8 * q]);
    }
    __syncthreads();

    float s0 = 0.f, ss0 = 0.f, s1 = 0.f, ss1 = 0.f;

    frag_ab wb_[2][4];
    {
        const unsigned short* wp = Wb + (size_t)((wave * 4 + 0) * 16 + m) * K_ + 8 * q;
#pragma unroll
        for (int s = 0; s < 4; ++s) wb_[0][s] = *(const frag_ab*)(wp + 32 * s);
    }

#pragma unroll
    for (int tt = 0; tt < 4; ++tt) {
        const int cur = tt & 1;
        if (tt < 3) {
            const unsigned short* wp = Wb + (size_t)((wave * 4 + tt + 1) * 16 + m) * K_ + 8 * q;
#pragma unroll
            for (int s = 0; s < 4; ++s) wb_[cur ^ 1][s] = *(const frag_ab*)(wp + 32 * s);
        }
        frag_cd acc0 = {0.f, 0.f, 0.f, 0.f};
        frag_cd acc1 = {0.f, 0.f, 0.f, 0.f};
#pragma unroll
        for (int s = 0; s < 4; ++s) {
            acc0 = __builtin_amdgcn_mfma_f32_16x16x32_bf16(wb_[cur][s], a0[s], acc0, 0, 0, 0);
            acc1 = __builtin_amdgcn_mfma_f32_16x16x32_bf16(wb_[cur][s], a1[s], acc1, 0, 0, 0);
        }
        const int nt  = wave * 4 + tt;
        const int col = nt * 16 + q * 4;
        const float4 bn = *(const float4*)(bias + col);
        const float bnv[4] = {bn.x, bn.y, bn.z, bn.w};
        float4 h0, h1;
#pragma unroll
        for (int reg = 0; reg < 4; ++reg) {
            const float z0 = acc0[reg] + bnv[reg];
            const float z1 = acc1[reg] + bnv[reg];
            const float v0 = z0 / (1.f + __expf(-z0));
            const float v1 = z1 / (1.f + __expf(-z1));
            s0 += v0; ss0 += v0 * v0;
            s1 += v1; ss1 += v1 * v1;
            ((float*)&h0)[reg] = v0;
            ((float*)&h1)[reg] = v1;
        }
        *(float4*)(&hs[m][col])         = h0;
        *(float4*)(&hs[NTOK_ + m][col]) = h1;
    }

    s0  += __shfl_xor(s0,  16, 64);  ss0 += __shfl_xor(ss0, 16, 64);
    s0  += __shfl_xor(s0,  32, 64);  ss0 += __shfl_xor(ss0, 32, 64);
    s1  += __shfl_xor(s1,  16, 64);  ss1 += __shfl_xor(ss1, 16, 64);
    s1  += __shfl_xor(s1,  32, 64);  ss1 += __shfl_xor(ss1, 32, 64);
    if (q == 0) {
        ps [m][wave]         = s0;  pss[m][wave]         = ss0;
        ps [NTOK_ + m][wave] = s1;  pss[NTOK_ + m][wave] = ss1;
    }
    __syncthreads();

    const float4 gm = *(const float4*)(gamma + lane * 4);
    const float4 bt = *(const float4*)(beta  + lane * 4);
#pragma unroll
    for (int qq = 0; qq < 8; ++qq) {
        const int n = wave * 8 + qq;
        const float4 p4  = *(const float4*)(&ps[n][0]);
        const float4 pq4 = *(const float4*)(&pss[n][0]);
        const float s_tot  = (p4.x  + p4.y)  + (p4.z  + p4.w);
        const float ss_tot = (pq4.x + pq4.y) + (pq4.z + pq4.w);
        const float mu   = s_tot * (1.f / D_);
        const float var  = ss_tot * (1.f / D_) - mu * mu;
        const float rsig = rsqrtf(var + LN_EPS);

        const float4 v = *(const float4*)(&hs[n][lane * 4]);
        f32x4 o;
        o.x = (v.x - mu) * rsig * gm.x + bt.x;
        o.y = (v.y - mu) * rsig * gm.y + bt.y;
        o.z = (v.z - mu) * rsig * gm.z + bt.z;
        o.w = (v.w - mu) * rsig * gm.w + bt.w;
        const size_t orow = ((size_t)(b0 + (n >> 4)) * NTOK_ + (n & 15)) * D_;
        __builtin_nontemporal_store(o, (f32x4*)(out + orow + lane * 4));
    }
}

extern "C" void kernel_launch(void* const* d_in, const int* in_sizes, int n_in,
                              void* d_out, int out_size, void* d_ws, size_t ws_size,
                              hipStream_t stream) {
    const int*   int_feats    = (const int*)  d_in[0];
    const int*   missing_mask = (const int*)  d_in[1];
    const int*   group_idx    = (const int*)  d_in[2];
    const float* emb_tables   = (const float*)d_in[3];
    const float* missing_emb  = (const float*)d_in[4];
    const float* W            = (const float*)d_in[5];
    const float* bias         = (const float*)d_in[6];
    const float* gamma        = (const float*)d_in[7];
    const float* beta         = (const float*)d_in[8];
    float* out = (float*)d_out;

    unsigned short* Wb = (unsigned short*)d_ws;                        // 64 KB
    const size_t wb_bytes  = (size_t)D_ * K_ * 2;                      // 65536
    const size_t tbl_bytes = (size_t)T_ * F_ * V_ * E_ * 2;            // 16,384,000
    const size_t mis_bytes = (size_t)T_ * F_ * E_ * 2;                 // 16,384
    _Float16* tblh = (_Float16*)((char*)d_ws + wb_bytes);
    _Float16* mish = (_Float16*)((char*)d_ws + wb_bytes + tbl_bytes);

    convert_w_kernel<<<(D_ * K_ / 2 + 255) / 256, 256, 0, stream>>>(W, (unsigned int*)Wb);

    if (ws_size >= wb_bytes + tbl_bytes + mis_bytes) {
        const int n8_tbl = T_ * F_ * V_ * E_ / 8;   // 1,024,000
        const int n8_mis = T_ * F_ * E_ / 8;        // 1,024
        convert_f16_kernel<<<(n8_tbl + 255) / 256, 256, 0, stream>>>(emb_tables, tblh, n8_tbl);
        convert_f16_kernel<<<(n8_mis + 255) / 256, 256, 0, stream>>>(missing_emb, mish, n8_mis);
        fused_tokenizer_kernel<<<B_ / RPB, 256, 0, stream>>>(
            int_feats, missing_mask, group_idx, tblh, mish,
            Wb, bias, gamma, beta, out);
    } else {
        fused_tokenizer_fp32_kernel<<<B_ / RPB, 256, 0, stream>>>(
            int_feats, missing_mask, group_idx, emb_tables, missing_emb,
            Wb, bias, gamma, beta, out);
    }
}

// Round 10
// 215.267 us; speedup vs baseline: 1.0550x; 1.0296x over previous
//
#include <hip/hip_runtime.h>
#include <math.h>

// Problem constants (match reference)
#define B_    8192
#define F_    64
#define V_    1000
#define E_    64
#define T_    2
#define NTOK_ 16
#define G_    4
#define D_    256
#define K_    128   // T*E
#define LN_EPS 1e-5f

#define RPB   2              // batch rows per block
#define TOK2  (NTOK_ * RPB)  // 32 tokens per block
#define XSP   136            // xs row stride in bf16 elements (128 + 8 pad)
#define HSP   260            // hs row stride in floats (256 + 4)

typedef __attribute__((ext_vector_type(8))) short    frag_ab;  // 8 bf16 = 4 VGPRs
typedef __attribute__((ext_vector_type(4))) float    frag_cd;  // 4 fp32 acc
typedef __attribute__((ext_vector_type(4))) float    f32x4;    // native vec4 (NT-store legal)
typedef __attribute__((ext_vector_type(8))) _Float16 h8;       // 8 fp16 = 16B

static __device__ __forceinline__ unsigned short f2bf(float f) {
    // round-to-nearest-even fp32 -> bf16 (values are finite here)
    unsigned int u = __float_as_uint(f);
    u += 0x7FFFu + ((u >> 16) & 1u);
    return (unsigned short)(u >> 16);
}

// ---- merged prologue: one launch does W->bf16, emb_tables->fp16, missing->fp16.
// Normal (cached) stores throughout: every byte written here is read by the
// fused kernel right after — warm L2/L3 is the point (r9's NT store on Wb
// forced the consumer's W reads to HBM).
// grid = 64 (W) + 4000 (table) + 4 (missing) = 4068 blocks, all ranges exact.
__global__ __launch_bounds__(256) void convert_all_kernel(
    const float* __restrict__ W,   unsigned int* __restrict__ Wb_packed,
    const float* __restrict__ tbl, _Float16* __restrict__ tblh,
    const float* __restrict__ mis, _Float16* __restrict__ mish)
{
    const int tid = threadIdx.x;
    const int blk = blockIdx.x;
    if (blk < 64) {
        const int i = blk * 256 + tid;              // < 16384 = D*K/2
        const float2 v = *(const float2*)(W + (size_t)i * 2);
        Wb_packed[i] = (unsigned int)f2bf(v.x) | ((unsigned int)f2bf(v.y) << 16);
    } else if (blk < 64 + 4000) {
        const int i = (blk - 64) * 256 + tid;       // < 1,024,000 = T*F*V*E/8
        const float4 a = *(const float4*)(tbl + (size_t)i * 8);
        const float4 b = *(const float4*)(tbl + (size_t)i * 8 + 4);
        h8 o;
        o[0] = (_Float16)a.x; o[1] = (_Float16)a.y; o[2] = (_Float16)a.z; o[3] = (_Float16)a.w;
        o[4] = (_Float16)b.x; o[5] = (_Float16)b.y; o[6] = (_Float16)b.z; o[7] = (_Float16)b.w;
        *(h8*)(tblh + (size_t)i * 8) = o;
    } else {
        const int i = (blk - 4064) * 256 + tid;     // < 1024 = T*F*E/8 (exact)
        const float4 a = *(const float4*)(mis + (size_t)i * 8);
        const float4 b = *(const float4*)(mis + (size_t)i * 8 + 4);
        h8 o;
        o[0] = (_Float16)a.x; o[1] = (_Float16)a.y; o[2] = (_Float16)a.z; o[3] = (_Float16)a.w;
        o[4] = (_Float16)b.x; o[5] = (_Float16)b.y; o[6] = (_Float16)b.z; o[7] = (_Float16)b.w;
        *(h8*)(mish + (size_t)i * 8) = o;
    }
}

// ---- standalone W convert (fallback path only) ----
__global__ __launch_bounds__(256) void convert_w_kernel(const float* __restrict__ W,
                                                        unsigned int* __restrict__ Wb_packed) {
    const int i = blockIdx.x * 256 + threadIdx.x;
    if (i < (D_ * K_) / 2) {
        const float2 v = *(const float2*)(W + (size_t)i * 2);
        Wb_packed[i] = (unsigned int)f2bf(v.x) | ((unsigned int)f2bf(v.y) << 16);
    }
}

// One block per TWO batch rows (grid 4096). 256 threads = 4 waves.
// r6 MLP structure (proven): 2-row W reuse + W double-buffer, deferred LN,
// launch_bounds(256,4), NT out stores. r9: fp16 gather (halved bytes+loads).
// r10: gather is depth-2 pipelined FOR REAL — all 16 loads (chunk A + B) plus
// the first W buffer are issued, then sched_barrier(0) pins them above the
// pool code (r8 failed because the compiler sank stage-B loads to their uses;
// VGPR stayed 52). vmcnt counting lets pool-A run while B is in flight.
__global__ __launch_bounds__(256, 4) void fused_tokenizer_kernel(
    const int*   __restrict__ int_feats,     // (B, F)
    const int*   __restrict__ missing_mask,  // (B, F)
    const int*   __restrict__ group_idx,     // (NTOK, G)
    const _Float16* __restrict__ tblh,       // (T, F, V, E) fp16
    const _Float16* __restrict__ mish,       // (T, F, E)    fp16
    const unsigned short* __restrict__ Wb,   // (D, K) bf16
    const float* __restrict__ bias,          // (D,)
    const float* __restrict__ gamma,         // (D,)
    const float* __restrict__ beta,          // (D,)
    float*       __restrict__ out)           // (B, NTOK, D)
{
    // hs (32x260 fp32 = 33.3 KB) aliases xs (32x136 bf16 = 8.7 KB).
    __shared__ __align__(16) char smem[TOK2 * HSP * 4];
    unsigned short (*xs)[XSP] = (unsigned short (*)[XSP])smem;
    float          (*hs)[HSP] = (float (*)[HSP])smem;

    __shared__ int   sid[RPB][F_];
    __shared__ int   smask[RPB][F_];
    __shared__ int   sg[NTOK_ * G_];
    __shared__ float ps [TOK2][4];   // per-wave partial sum   (token, wave)
    __shared__ float pss[TOK2][4];   // per-wave partial sumsq

    const int tid  = threadIdx.x;
    const int b0   = blockIdx.x * RPB;
    const int lane = tid & 63;
    const int wave = tid >> 6;
    const int m    = lane & 15;   // token index within a row (D col of MFMA result)
    const int q    = lane >> 4;   // quadrant

    if (tid < RPB * F_) {
        const int r = tid >> 6, f = tid & 63;
        sid[r][f]   = int_feats[(b0 + r) * F_ + f];
        smask[r][f] = missing_mask[(b0 + r) * F_ + f];
    }
    if (tid < F_) sg[tid] = group_idx[tid];   // NTOK*G == F == 64
    __syncthreads();

    // ---- early W prefetch: first W buffer issued before the gather, its
    // L2 latency hides under phase 1 (completes at the phase-1 barrier drain).
    frag_ab wb0[4];
    {
        const unsigned short* wp = Wb + (size_t)((wave * 4) * 16 + m) * K_ + 8 * q;
#pragma unroll
        for (int s = 0; s < 4; ++s) wb0[s] = *(const frag_ab*)(wp + 32 * s);
    }

    // ---- Phase 1: fp16 gather + mean-pool, depth-2 (both chunks' loads batched) ----
    // chunk c in [0,512): row = c>>8, n = (c>>4)&15, t = (c>>3)&1, e8 = c&7.
    // 8 consecutive lanes cover one 128B fp16 embedding row -> coalesced dwordx4.
    {
        const int cA = tid,       rowA = cA >> 8, nA = (cA >> 4) & 15, tA = (cA >> 3) & 1, e8A = cA & 7;
        const int cB = 256 + tid, rowB = cB >> 8, nB = (cB >> 4) & 15, tB = (cB >> 3) & 1, e8B = cB & 7;

        h8    evA[G_], mvA[G_], evB[G_], mvB[G_];
        float mkA[G_], mkB[G_];
#pragma unroll
        for (int g = 0; g < G_; ++g) {
            const int fA  = sg[nA * G_ + g];
            const int idA = sid[rowA][fA];
            evA[g] = *(const h8*)(tblh + ((size_t)((tA * F_ + fA) * V_) + idA) * E_ + e8A * 8);
            mvA[g] = *(const h8*)(mish + (size_t)(tA * F_ + fA) * E_ + e8A * 8);
            mkA[g] = (float)smask[rowA][fA];
        }
#pragma unroll
        for (int g = 0; g < G_; ++g) {
            const int fB  = sg[nB * G_ + g];
            const int idB = sid[rowB][fB];
            evB[g] = *(const h8*)(tblh + ((size_t)((tB * F_ + fB) * V_) + idB) * E_ + e8B * 8);
            mvB[g] = *(const h8*)(mish + (size_t)(tB * F_ + fB) * E_ + e8B * 8);
            mkB[g] = (float)smask[rowB][fB];
        }
        __builtin_amdgcn_sched_barrier(0);   // loads stay issued ABOVE the pools

        float accA[8] = {0.f,0.f,0.f,0.f,0.f,0.f,0.f,0.f};
#pragma unroll
        for (int g = 0; g < G_; ++g)
#pragma unroll
            for (int j = 0; j < 8; ++j)
                accA[j] += (float)evA[g][j] + mkA[g] * (float)mvA[g][j];
        unsigned int pkA[4];
#pragma unroll
        for (int jj = 0; jj < 4; ++jj)
            pkA[jj] = (unsigned int)f2bf(0.25f * accA[2 * jj])
                    | ((unsigned int)f2bf(0.25f * accA[2 * jj + 1]) << 16);
        *(uint4*)(&xs[rowA * NTOK_ + nA][(tA * 8 + e8A) * 8]) = make_uint4(pkA[0], pkA[1], pkA[2], pkA[3]);

        float accB[8] = {0.f,0.f,0.f,0.f,0.f,0.f,0.f,0.f};
#pragma unroll
        for (int g = 0; g < G_; ++g)
#pragma unroll
            for (int j = 0; j < 8; ++j)
                accB[j] += (float)evB[g][j] + mkB[g] * (float)mvB[g][j];
        unsigned int pkB[4];
#pragma unroll
        for (int jj = 0; jj < 4; ++jj)
            pkB[jj] = (unsigned int)f2bf(0.25f * accB[2 * jj])
                    | ((unsigned int)f2bf(0.25f * accB[2 * jj + 1]) << 16);
        *(uint4*)(&xs[rowB * NTOK_ + nB][(tB * 8 + e8B) * 8]) = make_uint4(pkB[0], pkB[1], pkB[2], pkB[3]);
    }
    __syncthreads();

    // ---- Phase 2: swapped-operand MFMA, 2 rows sharing W fragments ----
    frag_ab a0[4], a1[4];
#pragma unroll
    for (int s = 0; s < 4; ++s) {
        a0[s] = *(const frag_ab*)(&xs[m][32 * s + 8 * q]);
        a1[s] = *(const frag_ab*)(&xs[NTOK_ + m][32 * s + 8 * q]);
    }
    __syncthreads();   // all waves' xs reads done before hs writes (aliased)

    float s0 = 0.f, ss0 = 0.f, s1 = 0.f, ss1 = 0.f;

    frag_ab wb_[2][4];
#pragma unroll
    for (int s = 0; s < 4; ++s) wb_[0][s] = wb0[s];   // prefetched before phase 1

#pragma unroll
    for (int tt = 0; tt < 4; ++tt) {
        const int cur = tt & 1;           // compile-time after unroll
        if (tt < 3) {
            const unsigned short* wp = Wb + (size_t)((wave * 4 + tt + 1) * 16 + m) * K_ + 8 * q;
#pragma unroll
            for (int s = 0; s < 4; ++s) wb_[cur ^ 1][s] = *(const frag_ab*)(wp + 32 * s);
        }
        frag_cd acc0 = {0.f, 0.f, 0.f, 0.f};
        frag_cd acc1 = {0.f, 0.f, 0.f, 0.f};
#pragma unroll
        for (int s = 0; s < 4; ++s) {
            acc0 = __builtin_amdgcn_mfma_f32_16x16x32_bf16(wb_[cur][s], a0[s], acc0, 0, 0, 0);
            acc1 = __builtin_amdgcn_mfma_f32_16x16x32_bf16(wb_[cur][s], a1[s], acc1, 0, 0, 0);
        }
        const int nt  = wave * 4 + tt;
        const int col = nt * 16 + q * 4;
        const float4 bn = *(const float4*)(bias + col);
        const float bnv[4] = {bn.x, bn.y, bn.z, bn.w};
        float4 h0, h1;
#pragma unroll
        for (int reg = 0; reg < 4; ++reg) {
            const float z0 = acc0[reg] + bnv[reg];
            const float z1 = acc1[reg] + bnv[reg];
            const float v0 = z0 / (1.f + __expf(-z0));   // silu
            const float v1 = z1 / (1.f + __expf(-z1));
            s0 += v0; ss0 += v0 * v0;
            s1 += v1; ss1 += v1 * v1;
            ((float*)&h0)[reg] = v0;
            ((float*)&h1)[reg] = v1;
        }
        *(float4*)(&hs[m][col])         = h0;   // raw silu; LN applied at readout
        *(float4*)(&hs[NTOK_ + m][col]) = h1;
    }

    // reduce across the 4 lanes holding token m (lanes m, m+16, m+32, m+48)
    s0  += __shfl_xor(s0,  16, 64);  ss0 += __shfl_xor(ss0, 16, 64);
    s0  += __shfl_xor(s0,  32, 64);  ss0 += __shfl_xor(ss0, 32, 64);
    s1  += __shfl_xor(s1,  16, 64);  ss1 += __shfl_xor(ss1, 16, 64);
    s1  += __shfl_xor(s1,  32, 64);  ss1 += __shfl_xor(ss1, 32, 64);
    if (q == 0) {
        ps [m][wave]         = s0;  pss[m][wave]         = ss0;
        ps [NTOK_ + m][wave] = s1;  pss[NTOK_ + m][wave] = ss1;
    }
    __syncthreads();

    // ---- Phase 3: LN at readout + coalesced NT stores; wave w: tokens 8w..8w+7 ----
    const float4 gm = *(const float4*)(gamma + lane * 4);
    const float4 bt = *(const float4*)(beta  + lane * 4);
#pragma unroll
    for (int qq = 0; qq < 8; ++qq) {
        const int n = wave * 8 + qq;            // 0..31
        const float4 p4  = *(const float4*)(&ps[n][0]);
        const float4 pq4 = *(const float4*)(&pss[n][0]);
        const float s_tot  = (p4.x  + p4.y)  + (p4.z  + p4.w);
        const float ss_tot = (pq4.x + pq4.y) + (pq4.z + pq4.w);
        const float mu   = s_tot * (1.f / D_);
        const float var  = ss_tot * (1.f / D_) - mu * mu;
        const float rsig = rsqrtf(var + LN_EPS);

        const float4 v = *(const float4*)(&hs[n][lane * 4]);
        f32x4 o;
        o.x = (v.x - mu) * rsig * gm.x + bt.x;
        o.y = (v.y - mu) * rsig * gm.y + bt.y;
        o.z = (v.z - mu) * rsig * gm.z + bt.z;
        o.w = (v.w - mu) * rsig * gm.w + bt.w;
        const size_t orow = ((size_t)(b0 + (n >> 4)) * NTOK_ + (n & 15)) * D_;
        __builtin_nontemporal_store(o, (f32x4*)(out + orow + lane * 4));
    }
}

// ================= Fallback (fp32 gather, r6-proven) — used only if ws too small
__global__ __launch_bounds__(256, 4) void fused_tokenizer_fp32_kernel(
    const int*   __restrict__ int_feats,
    const int*   __restrict__ missing_mask,
    const int*   __restrict__ group_idx,
    const float* __restrict__ emb_tables,
    const float* __restrict__ missing_emb,
    const unsigned short* __restrict__ Wb,
    const float* __restrict__ bias,
    const float* __restrict__ gamma,
    const float* __restrict__ beta,
    float*       __restrict__ out)
{
    __shared__ __align__(16) char smem[TOK2 * HSP * 4];
    unsigned short (*xs)[XSP] = (unsigned short (*)[XSP])smem;
    float          (*hs)[HSP] = (float (*)[HSP])smem;

    __shared__ int   sid[RPB][F_];
    __shared__ int   smask[RPB][F_];
    __shared__ int   sg[NTOK_ * G_];
    __shared__ float ps [TOK2][4];
    __shared__ float pss[TOK2][4];

    const int tid  = threadIdx.x;
    const int b0   = blockIdx.x * RPB;
    const int lane = tid & 63;
    const int wave = tid >> 6;

    if (tid < RPB * F_) {
        const int r = tid >> 6, f = tid & 63;
        sid[r][f]   = int_feats[(b0 + r) * F_ + f];
        smask[r][f] = missing_mask[(b0 + r) * F_ + f];
    }
    if (tid < F_) sg[tid] = group_idx[tid];
    __syncthreads();

#pragma unroll
    for (int i = 0; i < 4; ++i) {
        const int c   = i * 256 + tid;
        const int row = c >> 9;
        const int cc  = c & 511;
        const int n   = cc >> 5;
        const int r4  = cc & 31;
        const int t   = r4 >> 4;
        const int e   = (r4 & 15) * 4;

        float4 ev[G_], mv[G_];
        float  mk[G_];
#pragma unroll
        for (int g = 0; g < G_; ++g) {
            const int f  = sg[n * G_ + g];
            const int id = sid[row][f];
            ev[g] = *(const float4*)(emb_tables + (((size_t)(t * F_ + f) * V_) + id) * E_ + e);
            mv[g] = *(const float4*)(missing_emb + (size_t)(t * F_ + f) * E_ + e);
            mk[g] = (float)smask[row][f];
        }
        float ax = 0.f, ay = 0.f, az = 0.f, aw = 0.f;
#pragma unroll
        for (int g = 0; g < G_; ++g) {
            ax += ev[g].x + mk[g] * mv[g].x;
            ay += ev[g].y + mk[g] * mv[g].y;
            az += ev[g].z + mk[g] * mv[g].z;
            aw += ev[g].w + mk[g] * mv[g].w;
        }
        union { unsigned int u[2]; } pk;
        pk.u[0] = (unsigned int)f2bf(0.25f * ax) | ((unsigned int)f2bf(0.25f * ay) << 16);
        pk.u[1] = (unsigned int)f2bf(0.25f * az) | ((unsigned int)f2bf(0.25f * aw) << 16);
        *(uint2*)(&xs[row * NTOK_ + n][r4 * 4]) = make_uint2(pk.u[0], pk.u[1]);
    }
    __syncthreads();

    const int m = lane & 15;
    const int q = lane >> 4;

    frag_ab a0[4], a1[4];
#pragma unroll
    for (int s = 0; s < 4; ++s) {
        a0[s] = *(const frag_ab*)(&xs[m][32 * s + 8 * q]);
        a1[s] = *(const frag_ab*)(&xs[NTOK_ + m][32 * s + 8 * q]);
    }
    __syncthreads();

    float s0 = 0.f, ss0 = 0.f, s1 = 0.f, ss1 = 0.f;

    frag_ab wb_[2][4];
    {
        const unsigned short* wp = Wb + (size_t)((wave * 4 + 0) * 16 + m) * K_ + 8 * q;
#pragma unroll
        for (int s = 0; s < 4; ++s) wb_[0][s] = *(const frag_ab*)(wp + 32 * s);
    }

#pragma unroll
    for (int tt = 0; tt < 4; ++tt) {
        const int cur = tt & 1;
        if (tt < 3) {
            const unsigned short* wp = Wb + (size_t)((wave * 4 + tt + 1) * 16 + m) * K_ + 8 * q;
#pragma unroll
            for (int s = 0; s < 4; ++s) wb_[cur ^ 1][s] = *(const frag_ab*)(wp + 32 * s);
        }
        frag_cd acc0 = {0.f, 0.f, 0.f, 0.f};
        frag_cd acc1 = {0.f, 0.f, 0.f, 0.f};
#pragma unroll
        for (int s = 0; s < 4; ++s) {
            acc0 = __builtin_amdgcn_mfma_f32_16x16x32_bf16(wb_[cur][s], a0[s], acc0, 0, 0, 0);
            acc1 = __builtin_amdgcn_mfma_f32_16x16x32_bf16(wb_[cur][s], a1[s], acc1, 0, 0, 0);
        }
        const int nt  = wave * 4 + tt;
        const int col = nt * 16 + q * 4;
        const float4 bn = *(const float4*)(bias + col);
        const float bnv[4] = {bn.x, bn.y, bn.z, bn.w};
        float4 h0, h1;
#pragma unroll
        for (int reg = 0; reg < 4; ++reg) {
            const float z0 = acc0[reg] + bnv[reg];
            const float z1 = acc1[reg] + bnv[reg];
            const float v0 = z0 / (1.f + __expf(-z0));
            const float v1 = z1 / (1.f + __expf(-z1));
            s0 += v0; ss0 += v0 * v0;
            s1 += v1; ss1 += v1 * v1;
            ((float*)&h0)[reg] = v0;
            ((float*)&h1)[reg] = v1;
        }
        *(float4*)(&hs[m][col])         = h0;
        *(float4*)(&hs[NTOK_ + m][col]) = h1;
    }

    s0  += __shfl_xor(s0,  16, 64);  ss0 += __shfl_xor(ss0, 16, 64);
    s0  += __shfl_xor(s0,  32, 64);  ss0 += __shfl_xor(ss0, 32, 64);
    s1  += __shfl_xor(s1,  16, 64);  ss1 += __shfl_xor(ss1, 16, 64);
    s1  += __shfl_xor(s1,  32, 64);  ss1 += __shfl_xor(ss1, 32, 64);
    if (q == 0) {
        ps [m][wave]         = s0;  pss[m][wave]         = ss0;
        ps [NTOK_ + m][wave] = s1;  pss[NTOK_ + m][wave] = ss1;
    }
    __syncthreads();

    const float4 gm = *(const float4*)(gamma + lane * 4);
    const float4 bt = *(const float4*)(beta  + lane * 4);
#pragma unroll
    for (int qq = 0; qq < 8; ++qq) {
        const int n = wave * 8 + qq;
        const float4 p4  = *(const float4*)(&ps[n][0]);
        const float4 pq4 = *(const float4*)(&pss[n][0]);
        const float s_tot  = (p4.x  + p4.y)  + (p4.z  + p4.w);
        const float ss_tot = (pq4.x + pq4.y) + (pq4.z + pq4.w);
        const float mu   = s_tot * (1.f / D_);
        const float var  = ss_tot * (1.f / D_) - mu * mu;
        const float rsig = rsqrtf(var + LN_EPS);

        const float4 v = *(const float4*)(&hs[n][lane * 4]);
        f32x4 o;
        o.x = (v.x - mu) * rsig * gm.x + bt.x;
        o.y = (v.y - mu) * rsig * gm.y + bt.y;
        o.z = (v.z - mu) * rsig * gm.z + bt.z;
        o.w = (v.w - mu) * rsig * gm.w + bt.w;
        const size_t orow = ((size_t)(b0 + (n >> 4)) * NTOK_ + (n & 15)) * D_;
        __builtin_nontemporal_store(o, (f32x4*)(out + orow + lane * 4));
    }
}

extern "C" void kernel_launch(void* const* d_in, const int* in_sizes, int n_in,
                              void* d_out, int out_size, void* d_ws, size_t ws_size,
                              hipStream_t stream) {
    const int*   int_feats    = (const int*)  d_in[0];
    const int*   missing_mask = (const int*)  d_in[1];
    const int*   group_idx    = (const int*)  d_in[2];
    const float* emb_tables   = (const float*)d_in[3];
    const float* missing_emb  = (const float*)d_in[4];
    const float* W            = (const float*)d_in[5];
    const float* bias         = (const float*)d_in[6];
    const float* gamma        = (const float*)d_in[7];
    const float* beta         = (const float*)d_in[8];
    float* out = (float*)d_out;

    unsigned short* Wb = (unsigned short*)d_ws;                        // 64 KB
    const size_t wb_bytes  = (size_t)D_ * K_ * 2;                      // 65536
    const size_t tbl_bytes = (size_t)T_ * F_ * V_ * E_ * 2;            // 16,384,000
    const size_t mis_bytes = (size_t)T_ * F_ * E_ * 2;                 // 16,384
    _Float16* tblh = (_Float16*)((char*)d_ws + wb_bytes);
    _Float16* mish = (_Float16*)((char*)d_ws + wb_bytes + tbl_bytes);

    if (ws_size >= wb_bytes + tbl_bytes + mis_bytes) {
        convert_all_kernel<<<64 + 4000 + 4, 256, 0, stream>>>(
            W, (unsigned int*)Wb, emb_tables, tblh, missing_emb, mish);
        fused_tokenizer_kernel<<<B_ / RPB, 256, 0, stream>>>(
            int_feats, missing_mask, group_idx, tblh, mish,
            Wb, bias, gamma, beta, out);
    } else {
        convert_w_kernel<<<(D_ * K_ / 2 + 255) / 256, 256, 0, stream>>>(W, (unsigned int*)Wb);
        fused_tokenizer_fp32_kernel<<<B_ / RPB, 256, 0, stream>>>(
            int_feats, missing_mask, group_idx, emb_tables, missing_emb,
            Wb, bias, gamma, beta, out);
    }
}